// Round 1
// baseline (312.468 us; speedup 1.0000x reference)
//
#include <hip/hip_runtime.h>

typedef short short8 __attribute__((ext_vector_type(8)));
typedef float floatx4 __attribute__((ext_vector_type(4)));
typedef float floatx16 __attribute__((ext_vector_type(16)));
typedef unsigned short ushort4v __attribute__((ext_vector_type(4)));

#define DEV static __device__ __forceinline__

// fp32 -> bf16 round-to-nearest-even
DEV unsigned short f2bf(float f) {
  unsigned int u = __builtin_bit_cast(unsigned int, f);
  u += 0x7fffu + ((u >> 16) & 1u);
  return (unsigned short)(u >> 16);
}

// pack two fp32 -> bf16x2 (round-half-up; P values positive, bias ~0.5 ulp)
DEV unsigned int pkbf2(float a, float b) {
  unsigned int ua = __builtin_bit_cast(unsigned int, a) + 0x8000u;
  unsigned int ub = __builtin_bit_cast(unsigned int, b) + 0x8000u;
  return (ua >> 16) | (ub & 0xffff0000u);
}

// async global->LDS, 16B per lane (dest = wave-uniform base + lane*16)
DEV void gload16(const unsigned short* g, unsigned short* l) {
  __builtin_amdgcn_global_load_lds((__attribute__((address_space(1))) void*)g,
                                   (__attribute__((address_space(3))) void*)l,
                                   16, 0, 0);
}

// ---------------------------------------------------------------------------
// Kernel 1: fp32 -> bf16 conversion for X (4M), Wq|Wk|Wv (3M concat), Wo (1M)
// ---------------------------------------------------------------------------
__global__ void convert_kernel(const float* __restrict__ hs, const float* __restrict__ Wq,
                               const float* __restrict__ Wk, const float* __restrict__ Wv,
                               const float* __restrict__ Wo,
                               unsigned short* __restrict__ xbf, unsigned short* __restrict__ wqkv,
                               unsigned short* __restrict__ wobf) {
  size_t i4 = ((size_t)blockIdx.x * 256 + threadIdx.x) * 4;
  const float* src;
  unsigned short* dst;
  if (i4 < 4194304) {
    src = hs + i4; dst = xbf + i4;
  } else if (i4 < 7340032) {
    size_t o = i4 - 4194304;
    size_t lo = o & 1048575;
    src = (o < 1048576) ? (Wq + lo) : ((o < 2097152) ? (Wk + lo) : (Wv + lo));
    dst = wqkv + o;
  } else {
    size_t o = i4 - 7340032;
    src = Wo + o; dst = wobf + o;
  }
  float4 v = *(const float4*)src;
  ushort4v u;
  u.x = f2bf(v.x); u.y = f2bf(v.y); u.z = f2bf(v.z); u.w = f2bf(v.w);
  *(ushort4v*)dst = u;
}

// ---------------------------------------------------------------------------
// Kernel 2: pack attention_mask int32 [B,S,S] -> bitmask [B,S,S/64] u64
// ---------------------------------------------------------------------------
__global__ void maskpack_kernel(const int* __restrict__ mask, unsigned long long* __restrict__ bits) {
  int w = blockIdx.x * 256 + threadIdx.x;  // 131072 words
  const int4* p = (const int4*)(mask + (size_t)w * 64);
  unsigned long long r = 0ull;
#pragma unroll
  for (int j = 0; j < 16; ++j) {
    int4 m = p[j];
    r |= (unsigned long long)(m.x != 0) << (j * 4 + 0);
    r |= (unsigned long long)(m.y != 0) << (j * 4 + 1);
    r |= (unsigned long long)(m.z != 0) << (j * 4 + 2);
    r |= (unsigned long long)(m.w != 0) << (j * 4 + 3);
  }
  bits[w] = r;
}

// ---------------------------------------------------------------------------
// Kernel 3: fused QKV projection. 128x128 tile, BK=32, 4 waves (2x2).
//   nb<16 (Q,K): swapped orientation C^T = W·X^T -> packed 8B stores to [b,h,s,d].
//   nb>=16 (V): normal orientation -> packed 8B stores to V^T [b,h,d,s].
// ---------------------------------------------------------------------------
__global__ void __launch_bounds__(256) qkv_gemm(
    const unsigned short* __restrict__ X, const unsigned short* __restrict__ W,
    const float* __restrict__ bq, const float* __restrict__ bk, const float* __restrict__ bv,
    unsigned short* __restrict__ Qb, unsigned short* __restrict__ Kb,
    unsigned short* __restrict__ Vt) {
  __shared__ __align__(16) unsigned short As[128 * 32];
  __shared__ __align__(16) unsigned short Bs[128 * 32];
  const int tid = threadIdx.x;
  const int lane = tid & 63, wv = tid >> 6;
  const int wm = wv >> 1, wn = wv & 1;
  const int quad = lane >> 4, l15 = lane & 15;
  const int mb = blockIdx.y, nb = blockIdx.x;
  const bool sw = (nb < 16);  // Q/K blocks: swapped operand orientation

  const unsigned short* ga = X + (size_t)(mb * 128 + (tid >> 2)) * 1024 + (tid & 3) * 8;
  const unsigned short* gb = W + (size_t)(nb * 128 + (tid >> 2)) * 1024 + (tid & 3) * 8;
  unsigned short* la1 = As + tid * 8;
  unsigned short* la2 = As + 2048 + tid * 8;
  unsigned short* lb1 = Bs + tid * 8;
  unsigned short* lb2 = Bs + 2048 + tid * 8;

  const int wx = sw ? wn : wm;  // X-tile row block
  const int ww = sw ? wm : wn;  // W-tile row block

  floatx4 acc[4][4] = {};
  for (int kt = 0; kt < 32; ++kt) {
    const int k0 = kt * 32;
    gload16(ga + k0, la1);
    gload16(ga + k0 + 65536, la2);   // +64 rows
    gload16(gb + k0, lb1);
    gload16(gb + k0 + 65536, lb2);
    __syncthreads();
    short8 xa[4], wb[4];
#pragma unroll
    for (int i = 0; i < 4; ++i) {
      xa[i] = *(const short8*)&As[(wx * 64 + i * 16 + l15) * 32 + quad * 8];
      wb[i] = *(const short8*)&Bs[(ww * 64 + i * 16 + l15) * 32 + quad * 8];
    }
    if (sw) {
#pragma unroll
      for (int mt = 0; mt < 4; ++mt)
#pragma unroll
        for (int nt = 0; nt < 4; ++nt)
          acc[mt][nt] = __builtin_amdgcn_mfma_f32_16x16x32_bf16(wb[mt], xa[nt], acc[mt][nt], 0, 0, 0);
    } else {
#pragma unroll
      for (int mt = 0; mt < 4; ++mt)
#pragma unroll
        for (int nt = 0; nt < 4; ++nt)
          acc[mt][nt] = __builtin_amdgcn_mfma_f32_16x16x32_bf16(xa[mt], wb[nt], acc[mt][nt], 0, 0, 0);
    }
    __syncthreads();
  }

  if (sw) {
    // rows (m) = W-cols, cols (n) = s. d varies along r -> packed 8B stores.
#pragma unroll
    for (int mt = 0; mt < 4; ++mt) {
      const int wc0 = nb * 128 + wm * 64 + mt * 16 + quad * 4;  // W-col for r=0
      const int mat = wc0 >> 10;          // 0=Q, 1=K
      const int nl0 = wc0 & 1023;
      const int hh = nl0 >> 6, d0 = nl0 & 63;
      const float4 b4 = *(const float4*)((mat ? bk : bq) + nl0);
      unsigned short* dst = mat ? Kb : Qb;
#pragma unroll
      for (int nt = 0; nt < 4; ++nt) {
        const int colx = mb * 128 + wn * 64 + nt * 16 + l15;    // s index
        const int bb = colx >> 11, s = colx & 2047;
        ushort4v pv;
        pv[0] = f2bf(acc[mt][nt][0] + b4.x);
        pv[1] = f2bf(acc[mt][nt][1] + b4.y);
        pv[2] = f2bf(acc[mt][nt][2] + b4.z);
        pv[3] = f2bf(acc[mt][nt][3] + b4.w);
        *(ushort4v*)&dst[((size_t)(bb * 16 + hh) * 2048 + s) * 64 + d0] = pv;
      }
    }
  } else {
    // V: normal orientation; s varies along r -> packed 8B stores into V^T.
#pragma unroll
    for (int nt = 0; nt < 4; ++nt) {
      const int col = nb * 128 + wn * 64 + nt * 16 + l15;  // in [2048,3072)
      const int nl = col & 1023;
      const float bias = bv[nl];
      const int hh = nl >> 6, d = nl & 63;
#pragma unroll
      for (int mt = 0; mt < 4; ++mt) {
        const int row0 = mb * 128 + wm * 64 + mt * 16 + quad * 4;
        const int bb = row0 >> 11, s = row0 & 2047;
        ushort4v pv;
#pragma unroll
        for (int r = 0; r < 4; ++r) pv[r] = f2bf(acc[mt][nt][r] + bias);
        *(ushort4v*)&Vt[((size_t)(bb * 16 + hh) * 64 + d) * 2048 + s] = pv;
      }
    }
  }
}

// ---------------------------------------------------------------------------
// Kernel 4: flash attention on 32x32x16 MFMA.
//   1024 blocks = 32 (b,h) x 32 q-tiles of 64. 2 waves x 32 q-rows.
//   St = K·Q^T per 32-k block: C col (lane&31) = q = PV A-operand m-index.
//   C->A k-remap: v_permlane32_swap_b32 — one swap fills two A-words (T12).
//   T14 async-STAGE: next K/V tile + mask words prefetched to regs during
//   compute; LDS writes happen just after the barrier. setprio around MFMAs.
//   Fixed-max softmax p = exp2(s*scale - 10). LDS: Ks 16KB + Vs 16KB.
// ---------------------------------------------------------------------------
__global__ void __launch_bounds__(128, 2) attn_kernel(
    const unsigned short* __restrict__ Qb, const unsigned short* __restrict__ Kb,
    const unsigned short* __restrict__ Vt, const unsigned long long* __restrict__ mbits,
    unsigned short* __restrict__ ctx) {
  __shared__ __align__(16) unsigned short Ks[128 * 64];   // [krow][d-chunks swizzled]
  __shared__ __align__(16) unsigned short Vs[64 * 128];   // [d][s-chunks swizzled]
  const int tid = threadIdx.x;            // 0..127
  const int lane = tid & 63, wv = tid >> 6;
  const int l31 = lane & 31, h = lane >> 5;
  const int pair = blockIdx.x >> 5, qt = blockIdx.x & 31;
  const int b_ = pair >> 4, hd = pair & 15;
  const int qg = qt * 64 + wv * 32 + l31;           // this lane's q row
  const size_t pbase = (size_t)pair * (2048 * 64);

  // Q B-frags: B[k=(lane>>5)*8+j][n=lane&31] -> lane reads Q[qg][ks*16+h*8 ..+8]
  short8 qf[4];
#pragma unroll
  for (int ks = 0; ks < 4; ++ks)
    qf[ks] = *(const short8*)(Qb + pbase + (size_t)qg * 64 + ks * 16 + h * 8);

  // staging addresses (it-independent swizzle: row&7 == (tid>>3)&7 / (tid>>4)&7)
  const unsigned short* kg = Kb + pbase + (size_t)(tid >> 3) * 64 + (tid & 7) * 8;
  const unsigned short* vg = Vt + (size_t)pair * (size_t)(64 * 2048) + (size_t)(tid >> 4) * 2048 + (tid & 15) * 8;
  unsigned short* klp = Ks + (tid >> 3) * 64 + (((tid & 7) ^ ((tid >> 3) & 7)) * 8);
  unsigned short* vlp = Vs + (tid >> 4) * 128 + (((tid & 15) ^ (((tid >> 4) & 7) << 1)) * 8);

  const unsigned long long* mrow = mbits + ((size_t)b_ * 2048 + qg) * 32;

  // prologue: prefetch tile 0 + mask words into registers (T14)
  short8 kreg[8], vreg[8];
#pragma unroll
  for (int it = 0; it < 8; ++it) kreg[it] = *(const short8*)(kg + it * 1024);
#pragma unroll
  for (int it = 0; it < 8; ++it) vreg[it] = *(const short8*)(vg + it * 16384);
  unsigned long long w0 = mrow[0], w1 = mrow[1];

  floatx16 acc_o[2] = {};
  float lacc[4] = {0.f, 0.f, 0.f, 0.f};
  const float SCL = 0.125f * 1.44269504088896340736f;  // 1/sqrt(64) * log2(e)
  const float NC = -10.0f;

  for (int kb16 = 0; kb16 < 16; ++kb16) {
    __syncthreads();   // previous tile fully consumed by both waves
    // LDS write of the prefetched tile (vmcnt wait covered by prior compute)
#pragma unroll
    for (int it = 0; it < 8; ++it) *(short8*)(klp + it * 1024) = kreg[it];
#pragma unroll
    for (int it = 0; it < 8; ++it) *(short8*)(vlp + it * 1024) = vreg[it];
    __syncthreads();

    // issue next tile's global loads now; they complete under this compute
    unsigned long long nw0 = 0ull, nw1 = 0ull;
    if (kb16 < 15) {
      const size_t ko = (size_t)(kb16 + 1) * 8192;
      const int vo = (kb16 + 1) * 128;
#pragma unroll
      for (int it = 0; it < 8; ++it) kreg[it] = *(const short8*)(kg + ko + it * 1024);
#pragma unroll
      for (int it = 0; it < 8; ++it) vreg[it] = *(const short8*)(vg + vo + it * 16384);
      nw0 = mrow[kb16 * 2 + 2];
      nw1 = mrow[kb16 * 2 + 3];
    }

    // St = K·Q^T : accs[kb] C-layout: row=k_local(32), col=q=lane&31
    floatx16 accs[4] = {};
    __builtin_amdgcn_s_setprio(1);
#pragma unroll
    for (int ks = 0; ks < 4; ++ks)
#pragma unroll
      for (int kb = 0; kb < 4; ++kb) {
        const int krow = kb * 32 + l31;
        short8 kf = *(const short8*)&Ks[krow * 64 + (((ks * 2 + h) ^ (krow & 7)) * 8)];
        accs[kb] = __builtin_amdgcn_mfma_f32_32x32x16_bf16(kf, qf[ks], accs[kb], 0, 0, 0);
      }
    __builtin_amdgcn_s_setprio(0);

    // mask (fast path: all bits set)
    if (__any((w0 & w1) != ~0ull)) {
#pragma unroll
      for (int kb = 0; kb < 4; ++kb) {
        const unsigned long long w = (kb < 2) ? w0 : w1;
#pragma unroll
        for (int reg = 0; reg < 16; ++reg) {
          const int kl = (reg & 3) + 8 * (reg >> 2) + 4 * h;
          const int bit = (kb & 1) * 32 + kl;
          if (!((w >> bit) & 1ull)) accs[kb][reg] = -6e9f;
        }
      }
    }

    // per 32-k C-block: exp2 + pack, then permlane32_swap into PV A-frags.
    // pk word contents (h half): pk[4u+0]={4h,4h+1}, pk[4u+1]={4h+2,4h+3},
    // pk[4u+2]={8+4h,..}, pk[4u+3]={8+4h+2,..} (k within 16-block u).
    // A-word w needs k=8h'+{2w,2w+1}: swap(pk0,pk2) -> {word0, word2},
    // swap(pk1,pk3) -> {word1, word3}  (hi(a)<->lo(b) half exchange).
#pragma unroll
    for (int kb = 0; kb < 4; ++kb) {
      unsigned int pk[8];
      float ls = 0.f;
#pragma unroll
      for (int i = 0; i < 8; ++i) {
        const float a = exp2f(fmaf(accs[kb][2 * i], SCL, NC));
        const float b = exp2f(fmaf(accs[kb][2 * i + 1], SCL, NC));
        ls += a + b;
        pk[i] = pkbf2(a, b);
      }
      lacc[kb] += ls;
#pragma unroll
      for (int u = 0; u < 2; ++u) {
        auto r02 = __builtin_amdgcn_permlane32_swap(pk[4 * u + 0], pk[4 * u + 2], false, false);
        auto r13 = __builtin_amdgcn_permlane32_swap(pk[4 * u + 1], pk[4 * u + 3], false, false);
        union { unsigned int w[4]; short8 s8; } af;
        af.w[0] = r02[0];
        af.w[1] = r13[0];
        af.w[2] = r02[1];
        af.w[3] = r13[1];
        const int t = kb * 2 + u;  // PV k-step (16 s-rows each)
        __builtin_amdgcn_s_setprio(1);
#pragma unroll
        for (int nt = 0; nt < 2; ++nt) {
          const int vrow = nt * 32 + l31;
          short8 vf = *(const short8*)&Vs[vrow * 128 + (((t * 2 + h) ^ ((vrow & 7) << 1)) * 8)];
          acc_o[nt] = __builtin_amdgcn_mfma_f32_32x32x16_bf16(af.s8, vf, acc_o[nt], 0, 0, 0);
        }
        __builtin_amdgcn_s_setprio(0);
      }
    }
    w0 = nw0; w1 = nw1;
  }

  // row sum finalize: halves hold complementary k partials for q=l31
  float lsum = (lacc[0] + lacc[1]) + (lacc[2] + lacc[3]);
  lsum += __shfl_xor(lsum, 32);
  const float rinv = 1.f / ((lsum > 0.f) ? lsum : 1.f);

  // epilogue: acc_o C-layout row=q_local, col=d_local; ctx[b, s, hd*64+d]
#pragma unroll
  for (int reg = 0; reg < 16; ++reg) {
    const int ql = (reg & 3) + 8 * (reg >> 2) + 4 * h;
    const float rl = __shfl(rinv, ql);
    const size_t base = ((size_t)b_ * 2048 + qt * 64 + wv * 32 + ql) * 1024 + hd * 64;
    ctx[base + l31]      = f2bf(acc_o[0][reg] * rl);
    ctx[base + 32 + l31] = f2bf(acc_o[1][reg] * rl);
  }
}

// ---------------------------------------------------------------------------
// Kernel 5: output projection. out[m][e] = sum_d ctx[m][d]*Wo[e][d] + bo[e]
//   M=4096, N=1024, fp32 output.
// ---------------------------------------------------------------------------
__global__ void __launch_bounds__(256) out_gemm(
    const unsigned short* __restrict__ C, const unsigned short* __restrict__ W,
    const float* __restrict__ bo, float* __restrict__ out) {
  __shared__ __align__(16) unsigned short As[128 * 32];
  __shared__ __align__(16) unsigned short Bs[128 * 32];
  const int tid = threadIdx.x;
  const int lane = tid & 63, wv = tid >> 6;
  const int wm = wv >> 1, wn = wv & 1;
  const int quad = lane >> 4, l15 = lane & 15;
  const int mb = blockIdx.y, nb = blockIdx.x;

  const unsigned short* ga = C + (size_t)(mb * 128 + (tid >> 2)) * 1024 + (tid & 3) * 8;
  const unsigned short* gb = W + (size_t)(nb * 128 + (tid >> 2)) * 1024 + (tid & 3) * 8;
  unsigned short* la1 = As + tid * 8;
  unsigned short* la2 = As + 2048 + tid * 8;
  unsigned short* lb1 = Bs + tid * 8;
  unsigned short* lb2 = Bs + 2048 + tid * 8;

  floatx4 acc[4][4] = {};
  for (int kt = 0; kt < 32; ++kt) {
    const int k0 = kt * 32;
    gload16(ga + k0, la1);
    gload16(ga + k0 + 65536, la2);
    gload16(gb + k0, lb1);
    gload16(gb + k0 + 65536, lb2);
    __syncthreads();
    short8 af[4], bfr[4];
#pragma unroll
    for (int i = 0; i < 4; ++i) {
      af[i]  = *(const short8*)&As[(wm * 64 + i * 16 + l15) * 32 + quad * 8];
      bfr[i] = *(const short8*)&Bs[(wn * 64 + i * 16 + l15) * 32 + quad * 8];
    }
#pragma unroll
    for (int mt = 0; mt < 4; ++mt)
#pragma unroll
      for (int nt = 0; nt < 4; ++nt)
        acc[mt][nt] = __builtin_amdgcn_mfma_f32_16x16x32_bf16(af[mt], bfr[nt], acc[mt][nt], 0, 0, 0);
    __syncthreads();
  }
#pragma unroll
  for (int nt = 0; nt < 4; ++nt) {
    const int col = nb * 128 + wn * 64 + nt * 16 + l15;
    const float bias = bo[col];
#pragma unroll
    for (int mt = 0; mt < 4; ++mt)
#pragma unroll
      for (int r = 0; r < 4; ++r) {
        const int row = mb * 128 + wm * 64 + mt * 16 + quad * 4 + r;
        out[(size_t)row * 1024 + col] = acc[mt][nt][r] + bias;
      }
  }
}

// ---------------------------------------------------------------------------
extern "C" void kernel_launch(void* const* d_in, const int* in_sizes, int n_in,
                              void* d_out, int out_size, void* d_ws, size_t ws_size,
                              hipStream_t stream) {
  const float* hs = (const float*)d_in[0];
  const int* mask = (const int*)d_in[1];
  const float* Wq = (const float*)d_in[2];
  const float* bq = (const float*)d_in[3];
  const float* Wk = (const float*)d_in[4];
  const float* bk = (const float*)d_in[5];
  const float* Wv = (const float*)d_in[6];
  const float* bv = (const float*)d_in[7];
  const float* Wo = (const float*)d_in[8];
  const float* bo = (const float*)d_in[9];
  float* out = (float*)d_out;

  char* ws = (char*)d_ws;
  unsigned short* xbf  = (unsigned short*)(ws + 0);          // 4M elems
  unsigned short* wqkv = (unsigned short*)(ws + 8388608);    // 3M
  unsigned short* wobf = (unsigned short*)(ws + 14680064);   // 1M
  unsigned short* Qb   = (unsigned short*)(ws + 16777216);   // 4M
  unsigned short* Kb   = (unsigned short*)(ws + 25165824);   // 4M
  unsigned short* Vt   = (unsigned short*)(ws + 33554432);   // 4M
  unsigned short* ctx  = (unsigned short*)(ws + 41943040);   // 4M
  unsigned long long* mbits = (unsigned long long*)(ws + 50331648);  // 131072 words

  convert_kernel<<<8192, 256, 0, stream>>>(hs, Wq, Wk, Wv, Wo, xbf, wqkv, wobf);
  maskpack_kernel<<<512, 256, 0, stream>>>(mask, mbits);
  qkv_gemm<<<dim3(24, 32), 256, 0, stream>>>(xbf, wqkv, bq, bk, bv, Qb, Kb, Vt);
  attn_kernel<<<1024, 128, 0, stream>>>(Qb, Kb, Vt, mbits, ctx);
  out_gemm<<<dim3(8, 32), 256, 0, stream>>>(ctx, wobf, bo, out);
}

// Round 2
// 260.828 us; speedup vs baseline: 1.1980x; 1.1980x over previous
//
#include <hip/hip_runtime.h>

typedef short short8 __attribute__((ext_vector_type(8)));
typedef float floatx4 __attribute__((ext_vector_type(4)));
typedef float floatx16 __attribute__((ext_vector_type(16)));
typedef unsigned short ushort4v __attribute__((ext_vector_type(4)));

#define DEV static __device__ __forceinline__

// fp32 -> bf16 round-to-nearest-even
DEV unsigned short f2bf(float f) {
  unsigned int u = __builtin_bit_cast(unsigned int, f);
  u += 0x7fffu + ((u >> 16) & 1u);
  return (unsigned short)(u >> 16);
}

// pack two fp32 -> bf16x2 (round-half-up; P values positive, bias ~0.5 ulp)
DEV unsigned int pkbf2(float a, float b) {
  unsigned int ua = __builtin_bit_cast(unsigned int, a) + 0x8000u;
  unsigned int ub = __builtin_bit_cast(unsigned int, b) + 0x8000u;
  return (ua >> 16) | (ub & 0xffff0000u);
}

// async global->LDS, 16B per lane (dest = wave-uniform base + lane*16)
DEV void gload16(const unsigned short* g, unsigned short* l) {
  __builtin_amdgcn_global_load_lds((__attribute__((address_space(1))) void*)g,
                                   (__attribute__((address_space(3))) void*)l,
                                   16, 0, 0);
}

// ---------------------------------------------------------------------------
// Kernel 1: fp32 -> bf16 conversion for X (4M), Wq|Wk|Wv (3M concat), Wo (1M)
// ---------------------------------------------------------------------------
__global__ void convert_kernel(const float* __restrict__ hs, const float* __restrict__ Wq,
                               const float* __restrict__ Wk, const float* __restrict__ Wv,
                               const float* __restrict__ Wo,
                               unsigned short* __restrict__ xbf, unsigned short* __restrict__ wqkv,
                               unsigned short* __restrict__ wobf) {
  size_t i4 = ((size_t)blockIdx.x * 256 + threadIdx.x) * 4;
  const float* src;
  unsigned short* dst;
  if (i4 < 4194304) {
    src = hs + i4; dst = xbf + i4;
  } else if (i4 < 7340032) {
    size_t o = i4 - 4194304;
    size_t lo = o & 1048575;
    src = (o < 1048576) ? (Wq + lo) : ((o < 2097152) ? (Wk + lo) : (Wv + lo));
    dst = wqkv + o;
  } else {
    size_t o = i4 - 7340032;
    src = Wo + o; dst = wobf + o;
  }
  float4 v = *(const float4*)src;
  ushort4v u;
  u.x = f2bf(v.x); u.y = f2bf(v.y); u.z = f2bf(v.z); u.w = f2bf(v.w);
  *(ushort4v*)dst = u;
}

// ---------------------------------------------------------------------------
// Kernel 2: pack attention_mask int32 [B,S,S] -> bitmask [B,S,S/64] u64
// ---------------------------------------------------------------------------
__global__ void maskpack_kernel(const int* __restrict__ mask, unsigned long long* __restrict__ bits) {
  int w = blockIdx.x * 256 + threadIdx.x;  // 131072 words
  const int4* p = (const int4*)(mask + (size_t)w * 64);
  unsigned long long r = 0ull;
#pragma unroll
  for (int j = 0; j < 16; ++j) {
    int4 m = p[j];
    r |= (unsigned long long)(m.x != 0) << (j * 4 + 0);
    r |= (unsigned long long)(m.y != 0) << (j * 4 + 1);
    r |= (unsigned long long)(m.z != 0) << (j * 4 + 2);
    r |= (unsigned long long)(m.w != 0) << (j * 4 + 3);
  }
  bits[w] = r;
}

// ---------------------------------------------------------------------------
// Kernel 3: fused QKV projection. 128x128 tile, BK=32, 4 waves (2x2).
//   nb<16 (Q,K): swapped orientation C^T = W·X^T -> packed 8B stores to [b,h,s,d].
//   nb>=16 (V): normal orientation -> packed 8B stores to V^T [b,h,d,s].
// ---------------------------------------------------------------------------
__global__ void __launch_bounds__(256) qkv_gemm(
    const unsigned short* __restrict__ X, const unsigned short* __restrict__ W,
    const float* __restrict__ bq, const float* __restrict__ bk, const float* __restrict__ bv,
    unsigned short* __restrict__ Qb, unsigned short* __restrict__ Kb,
    unsigned short* __restrict__ Vt) {
  __shared__ __align__(16) unsigned short As[128 * 32];
  __shared__ __align__(16) unsigned short Bs[128 * 32];
  const int tid = threadIdx.x;
  const int lane = tid & 63, wv = tid >> 6;
  const int wm = wv >> 1, wn = wv & 1;
  const int quad = lane >> 4, l15 = lane & 15;
  const int mb = blockIdx.y, nb = blockIdx.x;
  const bool sw = (nb < 16);  // Q/K blocks: swapped operand orientation

  const unsigned short* ga = X + (size_t)(mb * 128 + (tid >> 2)) * 1024 + (tid & 3) * 8;
  const unsigned short* gb = W + (size_t)(nb * 128 + (tid >> 2)) * 1024 + (tid & 3) * 8;
  unsigned short* la1 = As + tid * 8;
  unsigned short* la2 = As + 2048 + tid * 8;
  unsigned short* lb1 = Bs + tid * 8;
  unsigned short* lb2 = Bs + 2048 + tid * 8;

  const int wx = sw ? wn : wm;  // X-tile row block
  const int ww = sw ? wm : wn;  // W-tile row block

  floatx4 acc[4][4] = {};
  for (int kt = 0; kt < 32; ++kt) {
    const int k0 = kt * 32;
    gload16(ga + k0, la1);
    gload16(ga + k0 + 65536, la2);   // +64 rows
    gload16(gb + k0, lb1);
    gload16(gb + k0 + 65536, lb2);
    __syncthreads();
    short8 xa[4], wb[4];
#pragma unroll
    for (int i = 0; i < 4; ++i) {
      xa[i] = *(const short8*)&As[(wx * 64 + i * 16 + l15) * 32 + quad * 8];
      wb[i] = *(const short8*)&Bs[(ww * 64 + i * 16 + l15) * 32 + quad * 8];
    }
    if (sw) {
#pragma unroll
      for (int mt = 0; mt < 4; ++mt)
#pragma unroll
        for (int nt = 0; nt < 4; ++nt)
          acc[mt][nt] = __builtin_amdgcn_mfma_f32_16x16x32_bf16(wb[mt], xa[nt], acc[mt][nt], 0, 0, 0);
    } else {
#pragma unroll
      for (int mt = 0; mt < 4; ++mt)
#pragma unroll
        for (int nt = 0; nt < 4; ++nt)
          acc[mt][nt] = __builtin_amdgcn_mfma_f32_16x16x32_bf16(xa[mt], wb[nt], acc[mt][nt], 0, 0, 0);
    }
    __syncthreads();
  }

  if (sw) {
    // rows (m) = W-cols, cols (n) = s. d varies along r -> packed 8B stores.
#pragma unroll
    for (int mt = 0; mt < 4; ++mt) {
      const int wc0 = nb * 128 + wm * 64 + mt * 16 + quad * 4;  // W-col for r=0
      const int mat = wc0 >> 10;          // 0=Q, 1=K
      const int nl0 = wc0 & 1023;
      const int hh = nl0 >> 6, d0 = nl0 & 63;
      const float4 b4 = *(const float4*)((mat ? bk : bq) + nl0);
      unsigned short* dst = mat ? Kb : Qb;
#pragma unroll
      for (int nt = 0; nt < 4; ++nt) {
        const int colx = mb * 128 + wn * 64 + nt * 16 + l15;    // s index
        const int bb = colx >> 11, s = colx & 2047;
        ushort4v pv;
        pv[0] = f2bf(acc[mt][nt][0] + b4.x);
        pv[1] = f2bf(acc[mt][nt][1] + b4.y);
        pv[2] = f2bf(acc[mt][nt][2] + b4.z);
        pv[3] = f2bf(acc[mt][nt][3] + b4.w);
        *(ushort4v*)&dst[((size_t)(bb * 16 + hh) * 2048 + s) * 64 + d0] = pv;
      }
    }
  } else {
    // V: normal orientation; s varies along r -> packed 8B stores into V^T.
#pragma unroll
    for (int nt = 0; nt < 4; ++nt) {
      const int col = nb * 128 + wn * 64 + nt * 16 + l15;  // in [2048,3072)
      const int nl = col & 1023;
      const float bias = bv[nl];
      const int hh = nl >> 6, d = nl & 63;
#pragma unroll
      for (int mt = 0; mt < 4; ++mt) {
        const int row0 = mb * 128 + wm * 64 + mt * 16 + quad * 4;
        const int bb = row0 >> 11, s = row0 & 2047;
        ushort4v pv;
#pragma unroll
        for (int r = 0; r < 4; ++r) pv[r] = f2bf(acc[mt][nt][r] + bias);
        *(ushort4v*)&Vt[((size_t)(bb * 16 + hh) * 64 + d) * 2048 + s] = pv;
      }
    }
  }
}

// ---------------------------------------------------------------------------
// Kernel 4: flash attention on 32x32x16 MFMA.
//   512 blocks = 32 (b,h) x 16 q-tiles of 128. 4 waves x 32 q-rows.
//   K/V tiles (128 k) double-buffered in LDS, staged by global_load_lds with
//   PRE-SWIZZLED per-lane global source (linear LDS dest, rule #21):
//     K: content Ks[row][c'] = K[row][c' ^ (row&7)]  (src chunk lane-static)
//     V: content Vs[d][c']  = V^T[d][c' ^ ((d&7)<<1)]
//   Loop: issue gload_lds(t+1, buf^1) -> compute(t, buf) -> barrier (drains
//   vmcnt under ~600cy of compute). No register-resident tile (R1 lesson:
//   64 VGPR prefetch -> spills, WRITE_SIZE 8->70MB).
//   C->A k-remap via v_permlane32_swap_b32; setprio around MFMA clusters.
//   Fixed-max softmax p = exp2(s*scale - 10). LDS: 2*(16+16)KB = 64KB.
// ---------------------------------------------------------------------------
__global__ void __launch_bounds__(256, 2) attn_kernel(
    const unsigned short* __restrict__ Qb, const unsigned short* __restrict__ Kb,
    const unsigned short* __restrict__ Vt, const unsigned long long* __restrict__ mbits,
    unsigned short* __restrict__ ctx) {
  __shared__ __align__(16) unsigned short Ks[2 * 128 * 64];   // [buf][krow][d-chunks swz]
  __shared__ __align__(16) unsigned short Vs[2 * 64 * 128];   // [buf][d][s-chunks swz]
  const int tid = threadIdx.x;            // 0..255
  const int lane = tid & 63, wv = tid >> 6;
  const int l31 = lane & 31, h = lane >> 5;
  const int pair = blockIdx.x >> 4, qt = blockIdx.x & 15;
  const int b_ = pair >> 4, hd = pair & 15;
  const int qg = qt * 128 + wv * 32 + l31;          // this lane's q row
  const size_t pbase = (size_t)pair * (2048 * 64);
  const size_t vtb = (size_t)pair * (64 * 2048);

  // Q B-frags: B[k=(lane>>5)*8+j][n=lane&31] -> lane reads Q[qg][ks*16+h*8 ..+8]
  short8 qf[4];
#pragma unroll
  for (int ks = 0; ks < 4; ++ks)
    qf[ks] = *(const short8*)(Qb + pbase + (size_t)qg * 64 + ks * 16 + h * 8);

  // staging lane constants (element offsets within a 128-k tile)
  // K: 16 calls of 512 elems; wave wv does calls wv*4+i. row = j*8+(l>>3).
  const int kSrc = wv * 2048 + (lane >> 3) * 64 + (((lane & 7) ^ (lane >> 3)) * 8);
  const int kDst = wv * 2048 + lane * 8;
  // V: 16 calls; d = j*4+(l>>4); d&7 = 4*(i&1) + (l>>4).
  const int vSrc0 = wv * 32768 + (lane >> 4) * 2048 + (((lane & 15) ^ ((lane >> 4) << 1)) * 8);
  const int vSrc1 = wv * 32768 + (lane >> 4) * 2048 + (((lane & 15) ^ ((4 + (lane >> 4)) << 1)) * 8);
  const int vDst = wv * 2048 + lane * 8;

  const unsigned long long* mrow = mbits + ((size_t)b_ * 2048 + qg) * 32;

  // prologue: stage tile 0 into buffer 0
  {
    const unsigned short* kt = Kb + pbase;
#pragma unroll
    for (int i = 0; i < 4; ++i) gload16(kt + kSrc + i * 512, Ks + kDst + i * 512);
    const unsigned short* vt = Vt + vtb;
#pragma unroll
    for (int i = 0; i < 4; ++i)
      gload16(vt + ((i & 1) ? vSrc1 : vSrc0) + i * 8192, Vs + vDst + i * 512);
  }
  unsigned long long w0 = mrow[0], w1 = mrow[1];
  __syncthreads();

  floatx16 acc_o[2] = {};
  float lacc[4] = {0.f, 0.f, 0.f, 0.f};
  const float SCL = 0.125f * 1.44269504088896340736f;  // 1/sqrt(64) * log2(e)
  const float NC = -10.0f;

  for (int kb16 = 0; kb16 < 16; ++kb16) {
    const int cur = kb16 & 1;
    const unsigned short* Kcur = Ks + cur * 8192;
    const unsigned short* Vcur = Vs + cur * 8192;

    // issue next tile's async loads into the other buffer (complete by barrier)
    unsigned long long nw0 = 0ull, nw1 = 0ull;
    if (kb16 < 15) {
      unsigned short* Knxt = Ks + (cur ^ 1) * 8192;
      unsigned short* Vnxt = Vs + (cur ^ 1) * 8192;
      const unsigned short* kt = Kb + pbase + (size_t)(kb16 + 1) * 8192;
#pragma unroll
      for (int i = 0; i < 4; ++i) gload16(kt + kSrc + i * 512, Knxt + kDst + i * 512);
      const unsigned short* vt = Vt + vtb + (size_t)(kb16 + 1) * 128;
#pragma unroll
      for (int i = 0; i < 4; ++i)
        gload16(vt + ((i & 1) ? vSrc1 : vSrc0) + i * 8192, Vnxt + vDst + i * 512);
      nw0 = mrow[kb16 * 2 + 2];
      nw1 = mrow[kb16 * 2 + 3];
    }

    // St = K·Q^T : accs[kb] C-layout: row=k_local(32), col=q=lane&31
    floatx16 accs[4] = {};
    __builtin_amdgcn_s_setprio(1);
#pragma unroll
    for (int ks = 0; ks < 4; ++ks)
#pragma unroll
      for (int kb = 0; kb < 4; ++kb) {
        const int krow = kb * 32 + l31;
        short8 kf = *(const short8*)&Kcur[krow * 64 + (((ks * 2 + h) ^ (krow & 7)) * 8)];
        accs[kb] = __builtin_amdgcn_mfma_f32_32x32x16_bf16(kf, qf[ks], accs[kb], 0, 0, 0);
      }
    __builtin_amdgcn_s_setprio(0);

    // mask (fast path: all bits set)
    if (__any((w0 & w1) != ~0ull)) {
#pragma unroll
      for (int kb = 0; kb < 4; ++kb) {
        const unsigned long long w = (kb < 2) ? w0 : w1;
#pragma unroll
        for (int reg = 0; reg < 16; ++reg) {
          const int kl = (reg & 3) + 8 * (reg >> 2) + 4 * h;
          const int bit = (kb & 1) * 32 + kl;
          if (!((w >> bit) & 1ull)) accs[kb][reg] = -6e9f;
        }
      }
    }

    // per 32-k C-block: exp2 + pack, then permlane32_swap into PV A-frags.
    // pk word contents (h half): pk[4u+0]={4h,4h+1}, pk[4u+1]={4h+2,4h+3},
    // pk[4u+2]={8+4h,..}, pk[4u+3]={8+4h+2,..} (k within 16-block u).
    // A-word w needs k=8h'+{2w,2w+1}: swap(pk0,pk2) -> {word0, word2},
    // swap(pk1,pk3) -> {word1, word3}  (hi(a)<->lo(b) half exchange).
#pragma unroll
    for (int kb = 0; kb < 4; ++kb) {
      unsigned int pk[8];
      float ls = 0.f;
#pragma unroll
      for (int i = 0; i < 8; ++i) {
        const float a = exp2f(fmaf(accs[kb][2 * i], SCL, NC));
        const float b = exp2f(fmaf(accs[kb][2 * i + 1], SCL, NC));
        ls += a + b;
        pk[i] = pkbf2(a, b);
      }
      lacc[kb] += ls;
#pragma unroll
      for (int u = 0; u < 2; ++u) {
        auto r02 = __builtin_amdgcn_permlane32_swap(pk[4 * u + 0], pk[4 * u + 2], false, false);
        auto r13 = __builtin_amdgcn_permlane32_swap(pk[4 * u + 1], pk[4 * u + 3], false, false);
        union { unsigned int w[4]; short8 s8; } af;
        af.w[0] = r02[0];
        af.w[1] = r13[0];
        af.w[2] = r02[1];
        af.w[3] = r13[1];
        const int t = kb * 2 + u;  // PV k-step (16 s-rows each)
        __builtin_amdgcn_s_setprio(1);
#pragma unroll
        for (int nt = 0; nt < 2; ++nt) {
          const int vrow = nt * 32 + l31;
          short8 vf = *(const short8*)&Vcur[vrow * 128 + (((t * 2 + h) ^ ((vrow & 7) << 1)) * 8)];
          acc_o[nt] = __builtin_amdgcn_mfma_f32_32x32x16_bf16(af.s8, vf, acc_o[nt], 0, 0, 0);
        }
        __builtin_amdgcn_s_setprio(0);
      }
    }
    if (kb16 < 15) __syncthreads();   // drains vmcnt: next tile ready, buf reusable
    w0 = nw0; w1 = nw1;
  }

  // row sum finalize: halves hold complementary k partials for q=l31
  float lsum = (lacc[0] + lacc[1]) + (lacc[2] + lacc[3]);
  lsum += __shfl_xor(lsum, 32);
  const float rinv = 1.f / ((lsum > 0.f) ? lsum : 1.f);

  // epilogue: acc_o C-layout row=q_local, col=d_local; ctx[b, s, hd*64+d]
#pragma unroll
  for (int reg = 0; reg < 16; ++reg) {
    const int ql = (reg & 3) + 8 * (reg >> 2) + 4 * h;
    const float rl = __shfl(rinv, ql);
    const size_t base = ((size_t)b_ * 2048 + qt * 128 + wv * 32 + ql) * 1024 + hd * 64;
    ctx[base + l31]      = f2bf(acc_o[0][reg] * rl);
    ctx[base + 32 + l31] = f2bf(acc_o[1][reg] * rl);
  }
}

// ---------------------------------------------------------------------------
// Kernel 5: output projection. out[m][e] = sum_d ctx[m][d]*Wo[e][d] + bo[e]
//   M=4096, N=1024, fp32 output.
// ---------------------------------------------------------------------------
__global__ void __launch_bounds__(256) out_gemm(
    const unsigned short* __restrict__ C, const unsigned short* __restrict__ W,
    const float* __restrict__ bo, float* __restrict__ out) {
  __shared__ __align__(16) unsigned short As[128 * 32];
  __shared__ __align__(16) unsigned short Bs[128 * 32];
  const int tid = threadIdx.x;
  const int lane = tid & 63, wv = tid >> 6;
  const int wm = wv >> 1, wn = wv & 1;
  const int quad = lane >> 4, l15 = lane & 15;
  const int mb = blockIdx.y, nb = blockIdx.x;

  const unsigned short* ga = C + (size_t)(mb * 128 + (tid >> 2)) * 1024 + (tid & 3) * 8;
  const unsigned short* gb = W + (size_t)(nb * 128 + (tid >> 2)) * 1024 + (tid & 3) * 8;
  unsigned short* la1 = As + tid * 8;
  unsigned short* la2 = As + 2048 + tid * 8;
  unsigned short* lb1 = Bs + tid * 8;
  unsigned short* lb2 = Bs + 2048 + tid * 8;

  floatx4 acc[4][4] = {};
  for (int kt = 0; kt < 32; ++kt) {
    const int k0 = kt * 32;
    gload16(ga + k0, la1);
    gload16(ga + k0 + 65536, la2);
    gload16(gb + k0, lb1);
    gload16(gb + k0 + 65536, lb2);
    __syncthreads();
    short8 af[4], bfr[4];
#pragma unroll
    for (int i = 0; i < 4; ++i) {
      af[i]  = *(const short8*)&As[(wm * 64 + i * 16 + l15) * 32 + quad * 8];
      bfr[i] = *(const short8*)&Bs[(wn * 64 + i * 16 + l15) * 32 + quad * 8];
    }
#pragma unroll
    for (int mt = 0; mt < 4; ++mt)
#pragma unroll
      for (int nt = 0; nt < 4; ++nt)
        acc[mt][nt] = __builtin_amdgcn_mfma_f32_16x16x32_bf16(af[mt], bfr[nt], acc[mt][nt], 0, 0, 0);
    __syncthreads();
  }
#pragma unroll
  for (int nt = 0; nt < 4; ++nt) {
    const int col = nb * 128 + wn * 64 + nt * 16 + l15;
    const float bias = bo[col];
#pragma unroll
    for (int mt = 0; mt < 4; ++mt)
#pragma unroll
      for (int r = 0; r < 4; ++r) {
        const int row = mb * 128 + wm * 64 + mt * 16 + quad * 4 + r;
        out[(size_t)row * 1024 + col] = acc[mt][nt][r] + bias;
      }
  }
}

// ---------------------------------------------------------------------------
extern "C" void kernel_launch(void* const* d_in, const int* in_sizes, int n_in,
                              void* d_out, int out_size, void* d_ws, size_t ws_size,
                              hipStream_t stream) {
  const float* hs = (const float*)d_in[0];
  const int* mask = (const int*)d_in[1];
  const float* Wq = (const float*)d_in[2];
  const float* bq = (const float*)d_in[3];
  const float* Wk = (const float*)d_in[4];
  const float* bk = (const float*)d_in[5];
  const float* Wv = (const float*)d_in[6];
  const float* bv = (const float*)d_in[7];
  const float* Wo = (const float*)d_in[8];
  const float* bo = (const float*)d_in[9];
  float* out = (float*)d_out;

  char* ws = (char*)d_ws;
  unsigned short* xbf  = (unsigned short*)(ws + 0);          // 4M elems
  unsigned short* wqkv = (unsigned short*)(ws + 8388608);    // 3M
  unsigned short* wobf = (unsigned short*)(ws + 14680064);   // 1M
  unsigned short* Qb   = (unsigned short*)(ws + 16777216);   // 4M
  unsigned short* Kb   = (unsigned short*)(ws + 25165824);   // 4M
  unsigned short* Vt   = (unsigned short*)(ws + 33554432);   // 4M
  unsigned short* ctx  = (unsigned short*)(ws + 41943040);   // 4M
  unsigned long long* mbits = (unsigned long long*)(ws + 50331648);  // 131072 words

  convert_kernel<<<8192, 256, 0, stream>>>(hs, Wq, Wk, Wv, Wo, xbf, wqkv, wobf);
  maskpack_kernel<<<512, 256, 0, stream>>>(mask, mbits);
  qkv_gemm<<<dim3(24, 32), 256, 0, stream>>>(xbf, wqkv, bq, bk, bv, Qb, Kb, Vt);
  attn_kernel<<<512, 256, 0, stream>>>(Qb, Kb, Vt, mbits, ctx);
  out_gemm<<<dim3(8, 32), 256, 0, stream>>>(ctx, wobf, bo, out);
}